// Round 9
// baseline (301.856 us; speedup 1.0000x reference)
//
#include <hip/hip_runtime.h>
#include <math.h>

#define NHEADS 16

typedef __attribute__((ext_vector_type(8))) short bf16x8;
typedef __attribute__((ext_vector_type(4))) float f32x4;

__device__ inline short f2b(float f) {
  unsigned u = __float_as_uint(f);
  u += 0x7fffu + ((u >> 16) & 1u);
  return (short)(u >> 16);
}
__device__ inline float b2f(short s) {
  return __uint_as_float(((unsigned)(unsigned short)s) << 16);
}
__device__ inline void gld16(const void* g, void* l) {
  __builtin_amdgcn_global_load_lds(
      (const __attribute__((address_space(1))) unsigned int*)g,
      (__attribute__((address_space(3))) unsigned int*)l, 16, 0, 0);
}
#define MFMA16(a, b, c) __builtin_amdgcn_mfma_f32_16x16x32_bf16(a, b, c, 0, 0, 0)

// ---------------------------------------------------------------------------
// init: zero kmax slots (64) + mask flags (2)
// ---------------------------------------------------------------------------
__global__ __launch_bounds__(128) void initk(unsigned* __restrict__ p) {
  if (threadIdx.x < 66) p[threadIdx.x] = 0u;
}

// ---------------------------------------------------------------------------
// Fused prep + weight transpose. blocks 0..8191: convert x/ctx + masks
// (mask segs also OR-reduce nonzero bits into flags, atomic only if nonzero);
// 8192..8215: permuted biases; 8216..10263: W -> bf16 [n'][k].
// ---------------------------------------------------------------------------
__global__ __launch_bounds__(256) void prep_wt(
    const float* __restrict__ x, const float* __restrict__ ctx,
    const float* __restrict__ cm, const float* __restrict__ ppm,
    const float* __restrict__ cpm,
    const float* sabq, const float* sabk, const float* sabv,
    const float* cabk, const float* cabv, const float* cabq,
    const float* W0, const float* W1, const float* W2, const float* W3,
    const float* W4, const float* W5, const float* W6, const float* W7,
    short* __restrict__ XB, short* __restrict__ CTXB,
    short* __restrict__ MBSA, short* __restrict__ MBCA,
    float* __restrict__ qkvb, float* __restrict__ kvb,
    float* __restrict__ qpb, unsigned* __restrict__ mflags,
    short* __restrict__ WT) {
  __shared__ float t[64][65];
  const int blk = blockIdx.x;
  const int tid = threadIdx.x;
  const int n4 = 2048 * 1024 / 4;
  if (blk < 8192) {
    int seg = blk >> 11;
    int i = (blk & 2047) * 256 + tid;
    if (i >= n4) return;
    float4 va;
    short* out;
    if (seg == 0) { va = ((const float4*)x)[i]; out = XB; }
    else if (seg == 1) { va = ((const float4*)ctx)[i]; out = CTXB; }
    else if (seg == 2) {
      va = ((const float4*)cm)[i];
      float4 vb = ((const float4*)ppm)[i];
      va.x += vb.x; va.y += vb.y; va.z += vb.z; va.w += vb.w;
      out = MBSA;
    } else { va = ((const float4*)cpm)[i]; out = MBCA; }
    short4 s;
    s.x = f2b(va.x); s.y = f2b(va.y); s.z = f2b(va.z); s.w = f2b(va.w);
    ((short4*)out)[i] = s;
    if (seg >= 2) {
      unsigned ob = __float_as_uint(va.x) | __float_as_uint(va.y) |
                    __float_as_uint(va.z) | __float_as_uint(va.w);
      #pragma unroll
      for (int off = 1; off < 64; off <<= 1)
        ob |= (unsigned)__shfl_xor((int)ob, off, 64);
      if ((tid & 63) == 0 && ob) atomicOr(mflags + (seg - 2), ob);
    }
    return;
  }
  if (blk < 8216) {
    int i = (blk - 8192) * 256 + tid;
    if (i >= 6144) return;
    int j = i & 1023;
    int pj = ((j & 63) << 4) | (j >> 6);
    int sec = i >> 10;
    if (sec == 0) qkvb[j] = sabq[pj];
    else if (sec == 1) qkvb[1024 + j] = sabk[pj];
    else if (sec == 2) qkvb[2048 + j] = sabv[pj];
    else if (sec == 3) kvb[j] = cabk[pj];
    else if (sec == 4) kvb[1024 + j] = cabv[pj];
    else qpb[j] = cabq[pj];
    return;
  }
  const int blk2 = blk - 8216;
  const int wz = blk2 >> 8;
  const int rem = blk2 & 255;
  const float* W;
  switch (wz) {
    case 0: W = W0; break; case 1: W = W1; break;
    case 2: W = W2; break; case 3: W = W3; break;
    case 4: W = W4; break; case 5: W = W5; break;
    case 6: W = W6; break; default: W = W7; break;
  }
  const int permute = (wz < 6) ? 1 : 0;
  short* o = WT + (size_t)wz * 1024 * 1024;
  const int n0 = (rem & 15) * 64, k0 = (rem >> 4) * 64;
  const int cg = (tid & 15) * 4, rg = tid >> 4;
  #pragma unroll
  for (int r = 0; r < 4; ++r) {
    int kl = rg + r * 16;
    float4 v = *(const float4*)(W + (size_t)(k0 + kl) * 1024 + n0 + cg);
    t[kl][cg + 0] = v.x; t[kl][cg + 1] = v.y;
    t[kl][cg + 2] = v.z; t[kl][cg + 3] = v.w;
  }
  __syncthreads();
  #pragma unroll
  for (int r = 0; r < 4; ++r) {
    int nl = rg + r * 16;
    int n = n0 + nl;
    int nrow = permute ? (((n & 15) << 6) | (n >> 4)) : n;
    short4 s;
    s.x = f2b(t[cg + 0][nl]); s.y = f2b(t[cg + 1][nl]);
    s.z = f2b(t[cg + 2][nl]); s.w = f2b(t[cg + 3][nl]);
    *(short4*)(o + (size_t)nrow * 1024 + k0 + cg) = s;
  }
}

// ---------------------------------------------------------------------------
// GEMM core: 64 x TN tile, BK=64, 4 waves, chunk-XOR swizzled LDS.
// Modes: 0 fp32 flat; 1 bf16 flat; 2 head-major; 3 QKV fused; 4 KV fused.
// TN=128 modes 3/4 fuse kmax (row-norm max, atomicMax).
// ---------------------------------------------------------------------------
template <int TN>
__device__ __forceinline__ void gemm_core(
    const short* __restrict__ A, const short* __restrict__ Bt,
    const float* __restrict__ bias,
    void* __restrict__ C0, short* __restrict__ C1, short* __restrict__ C2,
    int mode, int relu, int bx, int by,
    unsigned* __restrict__ kout, short* As, short* Bs) {
  constexpr int NT = TN / 32;
  constexpr int BR = TN / 4;
  const int tid = threadIdx.x;
  const int w = tid >> 6, l = tid & 63;
  const int ln = l & 15, lq = l >> 4;
  const int wm = w >> 1, wn = w & 1;
  const int m0 = bx * 64, n0 = by * TN;
  const int K = 1024;

  f32x4 acc[2][NT];
  #pragma unroll
  for (int s = 0; s < 2; ++s)
    #pragma unroll
    for (int t = 0; t < NT; ++t) acc[s][t] = (f32x4){0.f, 0.f, 0.f, 0.f};

  const int srow = l >> 3;
  const int sch = (l & 7) ^ srow;
  const short* ga = A + (size_t)(m0 + w * 16 + srow) * K + sch * 8;
  const short* gb = Bt + (size_t)(n0 + w * BR + srow) * K + sch * 8;
  short* la = &As[w * 16 * 64];
  short* lb = &Bs[w * BR * 64];

  for (int k0 = 0; k0 < K; k0 += 64) {
    __syncthreads();
    gld16(ga + k0, la);
    gld16(ga + (size_t)8 * K + k0, la + 512);
    #pragma unroll
    for (int rb = 0; rb < BR / 8; ++rb)
      gld16(gb + (size_t)rb * 8 * K + k0, lb + rb * 512);
    __syncthreads();
    #pragma unroll
    for (int kc = 0; kc < 2; ++kc) {
      const int co = ((kc * 4 + lq) ^ (ln & 7)) * 8;
      bf16x8 af[2], bf[NT];
      af[0] = *(const bf16x8*)&As[(wm * 32 + ln) * 64 + co];
      af[1] = *(const bf16x8*)&As[(wm * 32 + 16 + ln) * 64 + co];
      #pragma unroll
      for (int t = 0; t < NT; ++t)
        bf[t] = *(const bf16x8*)&Bs[(wn * (TN / 2) + t * 16 + ln) * 64 + co];
      #pragma unroll
      for (int s = 0; s < 2; ++s)
        #pragma unroll
        for (int t = 0; t < NT; ++t)
          acc[s][t] = MFMA16(af[s], bf[t], acc[s][t]);
    }
  }

  float bv[NT];
  #pragma unroll
  for (int t = 0; t < NT; ++t) bv[t] = bias[n0 + wn * (TN / 2) + t * 16 + ln];

  #pragma unroll
  for (int s = 0; s < 2; ++s) {
    #pragma unroll
    for (int t = 0; t < NT; ++t) {
      #pragma unroll
      for (int r = 0; r < 4; ++r) {
        int m = m0 + wm * 32 + s * 16 + lq * 4 + r;
        int n = n0 + wn * (TN / 2) + t * 16 + ln;
        float v = acc[s][t][r] + bv[t];
        if (relu) v = fmaxf(v, 0.f);
        int bb = m >> 10, ii = m & 1023;
        if (mode == 0) {
          ((float*)C0)[(size_t)m * 1024 + n] = v;
        } else if (mode == 1) {
          ((short*)C0)[(size_t)m * 1024 + n] = f2b(v);
        } else if (mode == 2) {
          int hh = n >> 6, d = n & 63;
          ((short*)C0)[(((size_t)(bb * 16 + hh)) * 1024 + ii) * 64 + d] = f2b(v);
        } else if (mode == 3) {
          int sel = n >> 10, g = n & 1023;
          int hh = g >> 6, d = g & 63;
          if (sel == 0)
            ((short*)C0)[(((size_t)(bb * 16 + hh)) * 1024 + ii) * 64 + d] = f2b(v);
          else if (sel == 1)
            C1[(((size_t)(bb * 16 + hh)) * 1024 + ii) * 64 + d] = f2b(v);
          else
            C2[(((size_t)(bb * 16 + hh)) * 64 + d) * 1024 + ii] = f2b(v);
        } else {
          int sel = n >> 10, g = n & 1023;
          int hh = g >> 6, d = g & 63;
          if (sel == 0)
            C1[(((size_t)(bb * 16 + hh)) * 1024 + ii) * 64 + d] = f2b(v);
          else
            C2[(((size_t)(bb * 16 + hh)) * 64 + d) * 1024 + ii] = f2b(v);
        }
      }
    }
  }

  if constexpr (TN == 128) {
    const int nb = n0 + wn * 64;
    const int selw = nb >> 10;
    if ((mode == 3 && selw == 1) || (mode == 4 && selw == 0)) {
      const int slotbase = (mode == 3) ? 0 : 32;
      const int bb = m0 >> 10;
      const int hh = (nb & 1023) >> 6;
      float mx = 0.f;
      #pragma unroll
      for (int s = 0; s < 2; ++s)
        #pragma unroll
        for (int r = 0; r < 4; ++r) {
          float ss = 0.f;
          #pragma unroll
          for (int t = 0; t < 4; ++t) {
            float v = acc[s][t][r] + bv[t];
            ss += v * v;
          }
          ss += __shfl_xor(ss, 1, 64);
          ss += __shfl_xor(ss, 2, 64);
          ss += __shfl_xor(ss, 4, 64);
          ss += __shfl_xor(ss, 8, 64);
          mx = fmaxf(mx, ss);
        }
      mx = fmaxf(mx, __shfl_xor(mx, 16, 64));
      mx = fmaxf(mx, __shfl_xor(mx, 32, 64));
      if (l == 0)
        atomicMax(kout + slotbase + bb * 16 + hh, __float_as_uint(mx));
    }
  }
}

template <int TN>
__global__ __launch_bounds__(256) void gemmT(
    const short* __restrict__ A, const short* __restrict__ Bt,
    const float* __restrict__ bias,
    void* __restrict__ C0, short* __restrict__ C1, short* __restrict__ C2,
    int mode, int relu, int ny,
    const short* __restrict__ A2, const short* __restrict__ Bt2,
    const float* __restrict__ bias2,
    void* __restrict__ D0, short* __restrict__ D1, short* __restrict__ D2,
    int mode2, int relu2, int ny2,
    unsigned* __restrict__ kout) {
  __shared__ short As[64 * 64];
  __shared__ short Bs[TN * 64];
  if (blockIdx.z == 1) {
    A = A2; Bt = Bt2; bias = bias2;
    C0 = D0; C1 = D1; C2 = D2; mode = mode2; relu = relu2; ny = ny2;
  }
  if ((int)blockIdx.y >= ny) return;
  gemm_core<TN>(A, Bt, bias, C0, C1, C2, mode, relu, blockIdx.x, blockIdx.y,
                kout, As, Bs);
}

// ---------------------------------------------------------------------------
// Flash attention (z<2) with zero-mask fast path; z>=2 planes run a fused
// KV gemm (gemm_core<128> mode 4) into separate buffers (off critical path).
// out = (sum exp(s-M) V)/l + mask@V, head-major BF16 [bh][i][o].
// ---------------------------------------------------------------------------
__global__ __launch_bounds__(256) void attn_flash(
    const short* __restrict__ qh, const short* __restrict__ kh,
    const short* __restrict__ vt, const short* __restrict__ maskb,
    const unsigned* __restrict__ kmax, short* __restrict__ out,
    const unsigned* __restrict__ mflagp,
    const short* __restrict__ gA, const short* __restrict__ gBt,
    const float* __restrict__ gbias, short* __restrict__ gC1,
    short* __restrict__ gC2, unsigned* __restrict__ gkout) {
  __shared__ short Ks[128 * 64];
  __shared__ short Vs[64 * 128];
  __shared__ short Msk[64 * 128];
  __shared__ short Ps[4][16 * 72];
  __shared__ float Ml[64];

  const int z = blockIdx.z;
  if (z >= 2) {
    int gid = (z - 2) * 256 + blockIdx.y * 16 + blockIdx.x;
    gemm_core<128>(gA, gBt, gbias, nullptr, gC1, gC2, 4, 0,
                   gid & 31, gid >> 5, gkout, (short*)Ks, (short*)Vs);
    return;
  }

  const int tid = threadIdx.x;
  const int w = tid >> 6, l = tid & 63;
  const int ln = l & 15, lq = l >> 4;
  const int i0 = blockIdx.x * 64;
  const int b = z;
  const int bh = b * 16 + blockIdx.y;
  const size_t bho = (size_t)bh * 65536;
  const unsigned mflag = *mflagp;

  const short* qp = qh + bho + (size_t)(i0 + w * 16 + ln) * 64 + lq * 8;
  bf16x8 qf0 = *(const bf16x8*)qp;
  bf16x8 qf1 = *(const bf16x8*)(qp + 32);

  float ssq = 0.f;
  #pragma unroll
  for (int e = 0; e < 8; ++e) {
    float f0 = b2f(qf0[e]), f1 = b2f(qf1[e]);
    ssq += f0 * f0 + f1 * f1;
  }
  ssq += __shfl_xor(ssq, 16, 64);
  ssq += __shfl_xor(ssq, 32, 64);
  float km = sqrtf(__uint_as_float(kmax[bh])) * 1.005f;
  if (lq == 0) Ml[w * 16 + ln] = sqrtf(ssq) * km * 0.125f + 1e-3f;
  float Mr[4], lac[4];
  #pragma unroll
  for (int r = 0; r < 4; ++r) { Mr[r] = Ml[w * 16 + lq * 4 + r]; lac[r] = 0.f; }

  const int r8 = l >> 3;
  const int c8 = (l & 7) ^ r8;
  const int r4 = l >> 4;
  const int cva = (l & 15) ^ r4;
  const short* gkb = kh + bho + (size_t)(w * 32 + r8) * 64 + c8 * 8;
  const short* gvb = vt + bho + (size_t)(w * 16 + r4) * 1024;
  const short* gmb = maskb + ((size_t)(b * 1024 + i0 + w * 16 + r4)) * 1024;
  short* lkb = &Ks[w * 32 * 64];
  short* lvb = &Vs[w * 16 * 128];
  short* lmb = &Msk[w * 16 * 128];
  short* PsW = &Ps[w][0];

  f32x4 oa[4], mo[4];
  #pragma unroll
  for (int os = 0; os < 4; ++os) {
    oa[os] = (f32x4){0.f, 0.f, 0.f, 0.f};
    mo[os] = (f32x4){0.f, 0.f, 0.f, 0.f};
  }

  const int c0 = (lq ^ (ln & 7)) * 8;
  const int c1 = ((4 | lq) ^ (ln & 7)) * 8;

  for (int jt = 0; jt < 8; ++jt) {
    const int j0 = jt * 128;
    __syncthreads();
    #pragma unroll
    for (int gi = 0; gi < 4; ++gi)
      gld16(gkb + (size_t)(j0 + gi * 8) * 64, lkb + gi * 512);
    #pragma unroll
    for (int gi = 0; gi < 4; ++gi) {
      int cc = (cva ^ ((gi & 1) << 2)) * 8;
      gld16(gvb + (size_t)gi * 4096 + j0 + cc, lvb + gi * 512);
    }
    if (mflag) {
      #pragma unroll
      for (int gi = 0; gi < 4; ++gi) {
        int cc = (cva ^ ((gi & 1) << 2)) * 8;
        gld16(gmb + (size_t)gi * 4096 + j0 + cc, lmb + gi * 512);
      }
    }
    __syncthreads();

    #pragma unroll
    for (int jh = 0; jh < 2; ++jh) {
      f32x4 sa[4];
      #pragma unroll
      for (int js = 0; js < 4; ++js) {
        const short* kr = &Ks[(jh * 64 + js * 16 + ln) * 64];
        bf16x8 kb0 = *(const bf16x8*)(kr + c0);
        bf16x8 kb1 = *(const bf16x8*)(kr + c1);
        f32x4 s = (f32x4){0.f, 0.f, 0.f, 0.f};
        s = MFMA16(qf0, kb0, s);
        s = MFMA16(qf1, kb1, s);
        sa[js] = s;
      }
      #pragma unroll
      for (int js = 0; js < 4; ++js)
        #pragma unroll
        for (int r = 0; r < 4; ++r) {
          float p = __expf(sa[js][r] * 0.125f - Mr[r]);
          lac[r] += p;
          PsW[(lq * 4 + r) * 72 + js * 16 + ln] = f2b(p);
        }
      bf16x8 pa0 = *(const bf16x8*)&PsW[ln * 72 + lq * 8];
      bf16x8 pa1 = *(const bf16x8*)&PsW[ln * 72 + 32 + lq * 8];
      #pragma unroll
      for (int os = 0; os < 4; ++os) {
        const short* vr = &Vs[(os * 16 + ln) * 128 + jh * 64];
        bf16x8 vb0 = *(const bf16x8*)(vr + c0);
        bf16x8 vb1 = *(const bf16x8*)(vr + c1);
        oa[os] = MFMA16(pa0, vb0, oa[os]);
        oa[os] = MFMA16(pa1, vb1, oa[os]);
      }
      if (mflag) {
        const short* mr2 = &Msk[(w * 16 + ln) * 128 + jh * 64];
        bf16x8 ma0 = *(const bf16x8*)(mr2 + c0);
        bf16x8 ma1 = *(const bf16x8*)(mr2 + c1);
        #pragma unroll
        for (int os = 0; os < 4; ++os) {
          const short* vr = &Vs[(os * 16 + ln) * 128 + jh * 64];
          bf16x8 vb0 = *(const bf16x8*)(vr + c0);
          bf16x8 vb1 = *(const bf16x8*)(vr + c1);
          mo[os] = MFMA16(ma0, vb0, mo[os]);
          mo[os] = MFMA16(ma1, vb1, mo[os]);
        }
      }
    }
  }

  #pragma unroll
  for (int r = 0; r < 4; ++r) {
    lac[r] += __shfl_xor(lac[r], 1, 64);
    lac[r] += __shfl_xor(lac[r], 2, 64);
    lac[r] += __shfl_xor(lac[r], 4, 64);
    lac[r] += __shfl_xor(lac[r], 8, 64);
  }
  float inv[4];
  #pragma unroll
  for (int r = 0; r < 4; ++r) inv[r] = 1.f / lac[r];

  #pragma unroll
  for (int os = 0; os < 4; ++os)
    #pragma unroll
    for (int r = 0; r < 4; ++r) {
      int row = i0 + w * 16 + lq * 4 + r;
      int o = os * 16 + ln;
      out[bho + (size_t)row * 64 + o] = f2b(oa[os][r] * inv[r] + mo[os][r]);
    }
}

// ---------------------------------------------------------------------------
// LayerNorm + residual. inmode: 0 fp32 flat; 1 bf16 head-major; 2 bf16 flat.
// ---------------------------------------------------------------------------
__global__ __launch_bounds__(256) void ln_kernel(
    const void* __restrict__ xin, const short* __restrict__ res,
    const float* __restrict__ g, const float* __restrict__ be,
    void* __restrict__ outp, int out_bf16, int inmode) {
  const int row = blockIdx.x;
  const int tid = threadIdx.x;
  float4 v;
  if (inmode == 0) {
    v = ((const float4*)((const float*)xin + (size_t)row * 1024))[tid];
  } else if (inmode == 1) {
    int b = row >> 10, i = row & 1023;
    const short* base = (const short*)xin + (size_t)b * 16 * 65536 +
                        (size_t)i * 64;
    int o = tid >> 2, h0 = (tid & 3) * 4;
    v.x = b2f(base[(size_t)(h0 + 0) * 65536 + o]);
    v.y = b2f(base[(size_t)(h0 + 1) * 65536 + o]);
    v.z = b2f(base[(size_t)(h0 + 2) * 65536 + o]);
    v.w = b2f(base[(size_t)(h0 + 3) * 65536 + o]);
  } else {
    short4 s4 = ((const short4*)((const short*)xin + (size_t)row * 1024))[tid];
    v.x = b2f(s4.x); v.y = b2f(s4.y); v.z = b2f(s4.z); v.w = b2f(s4.w);
  }
  float s = v.x + v.y + v.z + v.w;
  float sq = v.x * v.x + v.y * v.y + v.z * v.z + v.w * v.w;
  #pragma unroll
  for (int off = 32; off > 0; off >>= 1) {
    s += __shfl_down(s, off, 64);
    sq += __shfl_down(sq, off, 64);
  }
  __shared__ float rs[4], rq[4], stat[2];
  int wave = tid >> 6, lane = tid & 63;
  if (lane == 0) { rs[wave] = s; rq[wave] = sq; }
  __syncthreads();
  if (tid == 0) {
    float S = rs[0] + rs[1] + rs[2] + rs[3];
    float Q = rq[0] + rq[1] + rq[2] + rq[3];
    float mean = S * (1.f / 1024.f);
    float var = Q * (1.f / 1024.f) - mean * mean;
    stat[0] = mean;
    stat[1] = rsqrtf(var + 1e-5f);
  }
  __syncthreads();
  float mean = stat[0], rstd = stat[1];
  float4 g4 = ((const float4*)g)[tid];
  float4 b4 = ((const float4*)be)[tid];
  short4 r4 = ((const short4*)(res + (size_t)row * 1024))[tid];
  float o0 = (v.x - mean) * rstd * g4.x + b4.x + b2f(r4.x);
  float o1 = (v.y - mean) * rstd * g4.y + b4.y + b2f(r4.y);
  float o2 = (v.z - mean) * rstd * g4.z + b4.z + b2f(r4.z);
  float o3 = (v.w - mean) * rstd * g4.w + b4.w + b2f(r4.w);
  if (out_bf16) {
    short4 o;
    o.x = f2b(o0); o.y = f2b(o1); o.z = f2b(o2); o.w = f2b(o3);
    ((short4*)outp)[(size_t)row * 256 + tid] = o;
  } else {
    float4 o = {o0, o1, o2, o3};
    ((float4*)outp)[(size_t)row * 256 + tid] = o;
  }
}

// ---------------------------------------------------------------------------
extern "C" void kernel_launch(void* const* d_in, const int* in_sizes, int n_in,
                              void* d_out, int out_size, void* d_ws, size_t ws_size,
                              hipStream_t stream) {
  const float* x    = (const float*)d_in[0];
  const float* ctx  = (const float*)d_in[1];
  const float* cm   = (const float*)d_in[2];
  const float* ppm  = (const float*)d_in[3];
  const float* cpm  = (const float*)d_in[4];
  const float* saWq = (const float*)d_in[5];
  const float* sabq = (const float*)d_in[6];
  const float* saWk = (const float*)d_in[7];
  const float* sabk = (const float*)d_in[8];
  const float* saWv = (const float*)d_in[9];
  const float* sabv = (const float*)d_in[10];
  const float* caWq = (const float*)d_in[11];
  const float* cabq = (const float*)d_in[12];
  const float* caWk = (const float*)d_in[13];
  const float* cabk = (const float*)d_in[14];
  const float* caWv = (const float*)d_in[15];
  const float* cabv = (const float*)d_in[16];
  const float* ln1g = (const float*)d_in[17];
  const float* ln1b = (const float*)d_in[18];
  const float* ln2g = (const float*)d_in[19];
  const float* ln2b = (const float*)d_in[20];
  const float* ln3g = (const float*)d_in[21];
  const float* ln3b = (const float*)d_in[22];
  const float* W1   = (const float*)d_in[23];
  const float* b1   = (const float*)d_in[24];
  const float* W2   = (const float*)d_in[25];
  const float* b2   = (const float*)d_in[26];

  char* ws = (char*)d_ws;
  const size_t MB = 1024 * 1024;
  short* WT       = (short*)(ws);              // 8 x 2MB bf16 [n'][k]
  float* qkvb     = (float*)(ws + 16 * MB);
  float* kvb      = (float*)(ws + 16 * MB + 16384);
  float* qpb      = (float*)(ws + 16 * MB + 32768);
  unsigned* kmaxu = (unsigned*)(ws + 16 * MB + 49152);  // 64 kmax + 2 flags
  unsigned* mflags = kmaxu + 64;
  short* MBSA  = (short*)(ws + 17 * MB);
  short* MBCA  = (short*)(ws + 21 * MB);
  short* XB    = (short*)(ws + 25 * MB);
  short* CTXB  = (short*)(ws + 29 * MB);
  short* QH    = (short*)(ws + 33 * MB);
  short* KH    = (short*)(ws + 37 * MB);
  short* VT    = (short*)(ws + 41 * MB);
  short* S3B   = (short*)(ws + 45 * MB);
  short* X1B   = (short*)(ws + 53 * MB);
  short* KH2   = (short*)(ws + 57 * MB);
  short* VT2   = (short*)(ws + 61 * MB);
  short* X2B   = MBSA;
  short* HB    = CTXB;
  float* outp  = (float*)d_out;

  dim3 lg(2048);
  const short* dsp = nullptr;
  const float* dfp = nullptr;

  // 0: zero control words
  initk<<<dim3(1), 128, 0, stream>>>(kmaxu);

  // 1: prep + weight transpose (+ mask nonzero flags)
  prep_wt<<<dim3(10264), 256, 0, stream>>>(
      x, ctx, cm, ppm, cpm, sabq, sabk, sabv, cabk, cabv, cabq,
      saWq, saWk, saWv, caWk, caWv, caWq, W1, W2,
      XB, CTXB, MBSA, MBCA, qkvb, kvb, qpb, mflags, WT);

  // 2: QKV (self), kmax fused
  gemmT<128><<<dim3(32, 24, 1), 256, 0, stream>>>(
      XB, WT, qkvb, QH, KH, VT, 3, 0, 24,
      dsp, dsp, dfp, nullptr, nullptr, nullptr, 0, 0, 0, kmaxu);

  // 3: self attention (z 0-1) + caKV gemm (z 2-3, off critical path)
  attn_flash<<<dim3(16, 16, 4), 256, 0, stream>>>(
      QH, KH, VT, MBSA, kmaxu, S3B, mflags,
      CTXB, WT + 3 * 1048576, kvb, KH2, VT2, kmaxu);

  // 4: LN1
  ln_kernel<<<lg, 256, 0, stream>>>(S3B, XB, ln1g, ln1b, X1B, 1, 1);

  // 5: cross Q
  gemmT<64><<<dim3(32, 16, 1), 256, 0, stream>>>(
      X1B, WT + 5 * 1048576, qpb, QH, nullptr, nullptr, 2, 0, 16,
      dsp, dsp, dfp, nullptr, nullptr, nullptr, 0, 0, 0, kmaxu);

  // 6: cross attention
  attn_flash<<<dim3(16, 16, 2), 256, 0, stream>>>(
      QH, KH2, VT2, MBCA, kmaxu + 32, S3B, mflags + 1,
      dsp, dsp, dfp, nullptr, nullptr, kmaxu);

  // 7: LN2
  ln_kernel<<<lg, 256, 0, stream>>>(S3B, X1B, ln2g, ln2b, X2B, 1, 1);

  // 8-9: MLP
  gemmT<64><<<dim3(32, 16, 1), 256, 0, stream>>>(
      X2B, WT + 6 * 1048576, b1, HB, nullptr, nullptr, 1, 1, 16,
      dsp, dsp, dfp, nullptr, nullptr, nullptr, 0, 0, 0, kmaxu);
  gemmT<64><<<dim3(32, 16, 1), 256, 0, stream>>>(
      HB, WT + 7 * 1048576, b2, S3B, nullptr, nullptr, 1, 0, 16,
      dsp, dsp, dfp, nullptr, nullptr, nullptr, 0, 0, 0, kmaxu);

  // 10: LN3 -> output
  ln_kernel<<<lg, 256, 0, stream>>>(S3B, X2B, ln3g, ln3b, outp, 0, 2);
}

// Round 10
// 295.440 us; speedup vs baseline: 1.0217x; 1.0217x over previous
//
#include <hip/hip_runtime.h>
#include <math.h>

#define NHEADS 16

typedef __attribute__((ext_vector_type(8))) short bf16x8;
typedef __attribute__((ext_vector_type(4))) float f32x4;

__device__ inline short f2b(float f) {
  unsigned u = __float_as_uint(f);
  u += 0x7fffu + ((u >> 16) & 1u);
  return (short)(u >> 16);
}
__device__ inline float b2f(short s) {
  return __uint_as_float(((unsigned)(unsigned short)s) << 16);
}
__device__ inline void gld16(const void* g, void* l) {
  __builtin_amdgcn_global_load_lds(
      (const __attribute__((address_space(1))) unsigned int*)g,
      (__attribute__((address_space(3))) unsigned int*)l, 16, 0, 0);
}
#define MFMA16(a, b, c) __builtin_amdgcn_mfma_f32_16x16x32_bf16(a, b, c, 0, 0, 0)

// ---------------------------------------------------------------------------
// init: zero kmax slots (64) + mask flags (2)
// ---------------------------------------------------------------------------
__global__ __launch_bounds__(128) void initk(unsigned* __restrict__ p) {
  if (threadIdx.x < 66) p[threadIdx.x] = 0u;
}

// ---------------------------------------------------------------------------
// Fused prep + weight transpose. blocks 0..8191: convert x/ctx + masks
// (mask segs OR-reduce nonzero bits into flags, atomic only if nonzero);
// 8192..8215: permuted biases; 8216..10263: W -> bf16 [n'][k].
// ---------------------------------------------------------------------------
__global__ __launch_bounds__(256) void prep_wt(
    const float* __restrict__ x, const float* __restrict__ ctx,
    const float* __restrict__ cm, const float* __restrict__ ppm,
    const float* __restrict__ cpm,
    const float* sabq, const float* sabk, const float* sabv,
    const float* cabk, const float* cabv, const float* cabq,
    const float* W0, const float* W1, const float* W2, const float* W3,
    const float* W4, const float* W5, const float* W6, const float* W7,
    short* __restrict__ XB, short* __restrict__ CTXB,
    short* __restrict__ MBSA, short* __restrict__ MBCA,
    float* __restrict__ qkvb, float* __restrict__ kvb,
    float* __restrict__ qpb, unsigned* __restrict__ mflags,
    short* __restrict__ WT) {
  __shared__ float t[64][65];
  const int blk = blockIdx.x;
  const int tid = threadIdx.x;
  const int n4 = 2048 * 1024 / 4;
  if (blk < 8192) {
    int seg = blk >> 11;
    int i = (blk & 2047) * 256 + tid;
    if (i >= n4) return;
    float4 va;
    short* out;
    if (seg == 0) { va = ((const float4*)x)[i]; out = XB; }
    else if (seg == 1) { va = ((const float4*)ctx)[i]; out = CTXB; }
    else if (seg == 2) {
      va = ((const float4*)cm)[i];
      float4 vb = ((const float4*)ppm)[i];
      va.x += vb.x; va.y += vb.y; va.z += vb.z; va.w += vb.w;
      out = MBSA;
    } else { va = ((const float4*)cpm)[i]; out = MBCA; }
    short4 s;
    s.x = f2b(va.x); s.y = f2b(va.y); s.z = f2b(va.z); s.w = f2b(va.w);
    ((short4*)out)[i] = s;
    if (seg >= 2) {
      unsigned ob = __float_as_uint(va.x) | __float_as_uint(va.y) |
                    __float_as_uint(va.z) | __float_as_uint(va.w);
      #pragma unroll
      for (int off = 1; off < 64; off <<= 1)
        ob |= (unsigned)__shfl_xor((int)ob, off, 64);
      if ((tid & 63) == 0 && ob) atomicOr(mflags + (seg - 2), ob);
    }
    return;
  }
  if (blk < 8216) {
    int i = (blk - 8192) * 256 + tid;
    if (i >= 6144) return;
    int j = i & 1023;
    int pj = ((j & 63) << 4) | (j >> 6);
    int sec = i >> 10;
    if (sec == 0) qkvb[j] = sabq[pj];
    else if (sec == 1) qkvb[1024 + j] = sabk[pj];
    else if (sec == 2) qkvb[2048 + j] = sabv[pj];
    else if (sec == 3) kvb[j] = cabk[pj];
    else if (sec == 4) kvb[1024 + j] = cabv[pj];
    else qpb[j] = cabq[pj];
    return;
  }
  const int blk2 = blk - 8216;
  const int wz = blk2 >> 8;
  const int rem = blk2 & 255;
  const float* W;
  switch (wz) {
    case 0: W = W0; break; case 1: W = W1; break;
    case 2: W = W2; break; case 3: W = W3; break;
    case 4: W = W4; break; case 5: W = W5; break;
    case 6: W = W6; break; default: W = W7; break;
  }
  const int permute = (wz < 6) ? 1 : 0;
  short* o = WT + (size_t)wz * 1024 * 1024;
  const int n0 = (rem & 15) * 64, k0 = (rem >> 4) * 64;
  const int cg = (tid & 15) * 4, rg = tid >> 4;
  #pragma unroll
  for (int r = 0; r < 4; ++r) {
    int kl = rg + r * 16;
    float4 v = *(const float4*)(W + (size_t)(k0 + kl) * 1024 + n0 + cg);
    t[kl][cg + 0] = v.x; t[kl][cg + 1] = v.y;
    t[kl][cg + 2] = v.z; t[kl][cg + 3] = v.w;
  }
  __syncthreads();
  #pragma unroll
  for (int r = 0; r < 4; ++r) {
    int nl = rg + r * 16;
    int n = n0 + nl;
    int nrow = permute ? (((n & 15) << 6) | (n >> 4)) : n;
    short4 s;
    s.x = f2b(t[cg + 0][nl]); s.y = f2b(t[cg + 1][nl]);
    s.z = f2b(t[cg + 2][nl]); s.w = f2b(t[cg + 3][nl]);
    *(short4*)(o + (size_t)nrow * 1024 + k0 + cg) = s;
  }
}

// ---------------------------------------------------------------------------
// GEMM, 64 x TN tile, BK=64, 4 waves (2x2), chunk-XOR swizzled LDS.
// Modes: 0 fp32 flat; 1 bf16 flat; 2 head-major; 3 QKV fused; 4 KV fused.
// Second arg set via blockIdx.z==1. TN=128 modes 3/4 fuse kmax.
// ---------------------------------------------------------------------------
template <int TN>
__global__ __launch_bounds__(256) void gemmT(
    const short* __restrict__ A, const short* __restrict__ Bt,
    const float* __restrict__ bias,
    void* __restrict__ C0, short* __restrict__ C1, short* __restrict__ C2,
    int mode, int relu, int ny,
    const short* __restrict__ A2, const short* __restrict__ Bt2,
    const float* __restrict__ bias2,
    void* __restrict__ D0, short* __restrict__ D1, short* __restrict__ D2,
    int mode2, int relu2, int ny2,
    unsigned* __restrict__ kout) {
  if (blockIdx.z == 1) {
    A = A2; Bt = Bt2; bias = bias2;
    C0 = D0; C1 = D1; C2 = D2; mode = mode2; relu = relu2; ny = ny2;
  }
  if ((int)blockIdx.y >= ny) return;

  constexpr int NT = TN / 32;
  constexpr int BR = TN / 4;
  __shared__ short As[64 * 64];
  __shared__ short Bs[TN * 64];
  const int tid = threadIdx.x;
  const int w = tid >> 6, l = tid & 63;
  const int ln = l & 15, lq = l >> 4;
  const int wm = w >> 1, wn = w & 1;
  const int m0 = blockIdx.x * 64, n0 = blockIdx.y * TN;
  const int K = 1024;

  f32x4 acc[2][NT];
  #pragma unroll
  for (int s = 0; s < 2; ++s)
    #pragma unroll
    for (int t = 0; t < NT; ++t) acc[s][t] = (f32x4){0.f, 0.f, 0.f, 0.f};

  const int srow = l >> 3;
  const int sch = (l & 7) ^ srow;
  const short* ga = A + (size_t)(m0 + w * 16 + srow) * K + sch * 8;
  const short* gb = Bt + (size_t)(n0 + w * BR + srow) * K + sch * 8;
  short* la = &As[w * 16 * 64];
  short* lb = &Bs[w * BR * 64];

  for (int k0 = 0; k0 < K; k0 += 64) {
    __syncthreads();
    gld16(ga + k0, la);
    gld16(ga + (size_t)8 * K + k0, la + 512);
    #pragma unroll
    for (int rb = 0; rb < BR / 8; ++rb)
      gld16(gb + (size_t)rb * 8 * K + k0, lb + rb * 512);
    __syncthreads();
    #pragma unroll
    for (int kc = 0; kc < 2; ++kc) {
      const int co = ((kc * 4 + lq) ^ (ln & 7)) * 8;
      bf16x8 af[2], bf[NT];
      af[0] = *(const bf16x8*)&As[(wm * 32 + ln) * 64 + co];
      af[1] = *(const bf16x8*)&As[(wm * 32 + 16 + ln) * 64 + co];
      #pragma unroll
      for (int t = 0; t < NT; ++t)
        bf[t] = *(const bf16x8*)&Bs[(wn * (TN / 2) + t * 16 + ln) * 64 + co];
      #pragma unroll
      for (int s = 0; s < 2; ++s)
        #pragma unroll
        for (int t = 0; t < NT; ++t)
          acc[s][t] = MFMA16(af[s], bf[t], acc[s][t]);
    }
  }

  float bv[NT];
  #pragma unroll
  for (int t = 0; t < NT; ++t) bv[t] = bias[n0 + wn * (TN / 2) + t * 16 + ln];

  #pragma unroll
  for (int s = 0; s < 2; ++s) {
    #pragma unroll
    for (int t = 0; t < NT; ++t) {
      #pragma unroll
      for (int r = 0; r < 4; ++r) {
        int m = m0 + wm * 32 + s * 16 + lq * 4 + r;
        int n = n0 + wn * (TN / 2) + t * 16 + ln;
        float v = acc[s][t][r] + bv[t];
        if (relu) v = fmaxf(v, 0.f);
        int bb = m >> 10, ii = m & 1023;
        if (mode == 0) {
          ((float*)C0)[(size_t)m * 1024 + n] = v;
        } else if (mode == 1) {
          ((short*)C0)[(size_t)m * 1024 + n] = f2b(v);
        } else if (mode == 2) {
          int hh = n >> 6, d = n & 63;
          ((short*)C0)[(((size_t)(bb * 16 + hh)) * 1024 + ii) * 64 + d] = f2b(v);
        } else if (mode == 3) {
          int sel = n >> 10, g = n & 1023;
          int hh = g >> 6, d = g & 63;
          if (sel == 0)
            ((short*)C0)[(((size_t)(bb * 16 + hh)) * 1024 + ii) * 64 + d] = f2b(v);
          else if (sel == 1)
            C1[(((size_t)(bb * 16 + hh)) * 1024 + ii) * 64 + d] = f2b(v);
          else
            C2[(((size_t)(bb * 16 + hh)) * 64 + d) * 1024 + ii] = f2b(v);
        } else {
          int sel = n >> 10, g = n & 1023;
          int hh = g >> 6, d = g & 63;
          if (sel == 0)
            C1[(((size_t)(bb * 16 + hh)) * 1024 + ii) * 64 + d] = f2b(v);
          else
            C2[(((size_t)(bb * 16 + hh)) * 64 + d) * 1024 + ii] = f2b(v);
        }
      }
    }
  }

  if constexpr (TN == 128) {
    const int nb = n0 + wn * 64;
    const int selw = nb >> 10;
    if ((mode == 3 && selw == 1) || (mode == 4 && selw == 0)) {
      const int slotbase = (mode == 3) ? 0 : 32;
      const int bb = m0 >> 10;
      const int hh = (nb & 1023) >> 6;
      float mx = 0.f;
      #pragma unroll
      for (int s = 0; s < 2; ++s)
        #pragma unroll
        for (int r = 0; r < 4; ++r) {
          float ss = 0.f;
          #pragma unroll
          for (int t = 0; t < 4; ++t) {
            float v = acc[s][t][r] + bv[t];
            ss += v * v;
          }
          ss += __shfl_xor(ss, 1, 64);
          ss += __shfl_xor(ss, 2, 64);
          ss += __shfl_xor(ss, 4, 64);
          ss += __shfl_xor(ss, 8, 64);
          mx = fmaxf(mx, ss);
        }
      mx = fmaxf(mx, __shfl_xor(mx, 16, 64));
      mx = fmaxf(mx, __shfl_xor(mx, 32, 64));
      if (l == 0)
        atomicMax(kout + slotbase + bb * 16 + hh, __float_as_uint(mx));
    }
  }
}

// ---------------------------------------------------------------------------
// Flash attention, 128-row j-tiles, zero-mask fast path (block-uniform flag).
// out = (sum exp(s-M) V)/l + mask@V, head-major BF16 [bh][i][o].
// grid (16 i-tiles, 16 h, 2 b), 4 waves.
// ---------------------------------------------------------------------------
__global__ __launch_bounds__(256) void attn_flash(
    const short* __restrict__ qh, const short* __restrict__ kh,
    const short* __restrict__ vt, const short* __restrict__ maskb,
    const unsigned* __restrict__ kmax, short* __restrict__ out,
    const unsigned* __restrict__ mflagp) {
  __shared__ short Ks[128 * 64];
  __shared__ short Vs[64 * 128];
  __shared__ short Msk[64 * 128];
  __shared__ short Ps[4][16 * 72];
  __shared__ float Ml[64];
  const int tid = threadIdx.x;
  const int w = tid >> 6, l = tid & 63;
  const int ln = l & 15, lq = l >> 4;
  const int i0 = blockIdx.x * 64;
  const int b = blockIdx.z;
  const int bh = b * 16 + blockIdx.y;
  const size_t bho = (size_t)bh * 65536;
  const unsigned mflag = *mflagp;

  const short* qp = qh + bho + (size_t)(i0 + w * 16 + ln) * 64 + lq * 8;
  bf16x8 qf0 = *(const bf16x8*)qp;
  bf16x8 qf1 = *(const bf16x8*)(qp + 32);

  float ssq = 0.f;
  #pragma unroll
  for (int e = 0; e < 8; ++e) {
    float f0 = b2f(qf0[e]), f1 = b2f(qf1[e]);
    ssq += f0 * f0 + f1 * f1;
  }
  ssq += __shfl_xor(ssq, 16, 64);
  ssq += __shfl_xor(ssq, 32, 64);
  float km = sqrtf(__uint_as_float(kmax[bh])) * 1.005f;
  if (lq == 0) Ml[w * 16 + ln] = sqrtf(ssq) * km * 0.125f + 1e-3f;
  float Mr[4], lac[4];
  #pragma unroll
  for (int r = 0; r < 4; ++r) { Mr[r] = Ml[w * 16 + lq * 4 + r]; lac[r] = 0.f; }

  const int r8 = l >> 3;
  const int c8 = (l & 7) ^ r8;
  const int r4 = l >> 4;
  const int cva = (l & 15) ^ r4;
  const short* gkb = kh + bho + (size_t)(w * 32 + r8) * 64 + c8 * 8;
  const short* gvb = vt + bho + (size_t)(w * 16 + r4) * 1024;
  const short* gmb = maskb + ((size_t)(b * 1024 + i0 + w * 16 + r4)) * 1024;
  short* lkb = &Ks[w * 32 * 64];
  short* lvb = &Vs[w * 16 * 128];
  short* lmb = &Msk[w * 16 * 128];
  short* PsW = &Ps[w][0];

  f32x4 oa[4], mo[4];
  #pragma unroll
  for (int os = 0; os < 4; ++os) {
    oa[os] = (f32x4){0.f, 0.f, 0.f, 0.f};
    mo[os] = (f32x4){0.f, 0.f, 0.f, 0.f};
  }

  const int c0 = (lq ^ (ln & 7)) * 8;
  const int c1 = ((4 | lq) ^ (ln & 7)) * 8;

  for (int jt = 0; jt < 8; ++jt) {
    const int j0 = jt * 128;
    __syncthreads();
    #pragma unroll
    for (int gi = 0; gi < 4; ++gi)
      gld16(gkb + (size_t)(j0 + gi * 8) * 64, lkb + gi * 512);
    #pragma unroll
    for (int gi = 0; gi < 4; ++gi) {
      int cc = (cva ^ ((gi & 1) << 2)) * 8;
      gld16(gvb + (size_t)gi * 4096 + j0 + cc, lvb + gi * 512);
    }
    if (mflag) {
      #pragma unroll
      for (int gi = 0; gi < 4; ++gi) {
        int cc = (cva ^ ((gi & 1) << 2)) * 8;
        gld16(gmb + (size_t)gi * 4096 + j0 + cc, lmb + gi * 512);
      }
    }
    __syncthreads();

    #pragma unroll
    for (int jh = 0; jh < 2; ++jh) {
      f32x4 sa[4];
      #pragma unroll
      for (int js = 0; js < 4; ++js) {
        const short* kr = &Ks[(jh * 64 + js * 16 + ln) * 64];
        bf16x8 kb0 = *(const bf16x8*)(kr + c0);
        bf16x8 kb1 = *(const bf16x8*)(kr + c1);
        f32x4 s = (f32x4){0.f, 0.f, 0.f, 0.f};
        s = MFMA16(qf0, kb0, s);
        s = MFMA16(qf1, kb1, s);
        sa[js] = s;
      }
      #pragma unroll
      for (int js = 0; js < 4; ++js)
        #pragma unroll
        for (int r = 0; r < 4; ++r) {
          float p = __expf(sa[js][r] * 0.125f - Mr[r]);
          lac[r] += p;
          PsW[(lq * 4 + r) * 72 + js * 16 + ln] = f2b(p);
        }
      bf16x8 pa0 = *(const bf16x8*)&PsW[ln * 72 + lq * 8];
      bf16x8 pa1 = *(const bf16x8*)&PsW[ln * 72 + 32 + lq * 8];
      #pragma unroll
      for (int os = 0; os < 4; ++os) {
        const short* vr = &Vs[(os * 16 + ln) * 128 + jh * 64];
        bf16x8 vb0 = *(const bf16x8*)(vr + c0);
        bf16x8 vb1 = *(const bf16x8*)(vr + c1);
        oa[os] = MFMA16(pa0, vb0, oa[os]);
        oa[os] = MFMA16(pa1, vb1, oa[os]);
      }
      if (mflag) {
        const short* mr2 = &Msk[(w * 16 + ln) * 128 + jh * 64];
        bf16x8 ma0 = *(const bf16x8*)(mr2 + c0);
        bf16x8 ma1 = *(const bf16x8*)(mr2 + c1);
        #pragma unroll
        for (int os = 0; os < 4; ++os) {
          const short* vr = &Vs[(os * 16 + ln) * 128 + jh * 64];
          bf16x8 vb0 = *(const bf16x8*)(vr + c0);
          bf16x8 vb1 = *(const bf16x8*)(vr + c1);
          mo[os] = MFMA16(ma0, vb0, mo[os]);
          mo[os] = MFMA16(ma1, vb1, mo[os]);
        }
      }
    }
  }

  #pragma unroll
  for (int r = 0; r < 4; ++r) {
    lac[r] += __shfl_xor(lac[r], 1, 64);
    lac[r] += __shfl_xor(lac[r], 2, 64);
    lac[r] += __shfl_xor(lac[r], 4, 64);
    lac[r] += __shfl_xor(lac[r], 8, 64);
  }
  float inv[4];
  #pragma unroll
  for (int r = 0; r < 4; ++r) inv[r] = 1.f / lac[r];

  #pragma unroll
  for (int os = 0; os < 4; ++os)
    #pragma unroll
    for (int r = 0; r < 4; ++r) {
      int row = i0 + w * 16 + lq * 4 + r;
      int o = os * 16 + ln;
      out[bho + (size_t)row * 64 + o] = f2b(oa[os][r] * inv[r] + mo[os][r]);
    }
}

// ---------------------------------------------------------------------------
// LayerNorm + residual. inmode: 0 fp32 flat; 1 bf16 head-major; 2 bf16 flat.
// ---------------------------------------------------------------------------
__global__ __launch_bounds__(256) void ln_kernel(
    const void* __restrict__ xin, const short* __restrict__ res,
    const float* __restrict__ g, const float* __restrict__ be,
    void* __restrict__ outp, int out_bf16, int inmode) {
  const int row = blockIdx.x;
  const int tid = threadIdx.x;
  float4 v;
  if (inmode == 0) {
    v = ((const float4*)((const float*)xin + (size_t)row * 1024))[tid];
  } else if (inmode == 1) {
    int b = row >> 10, i = row & 1023;
    const short* base = (const short*)xin + (size_t)b * 16 * 65536 +
                        (size_t)i * 64;
    int o = tid >> 2, h0 = (tid & 3) * 4;
    v.x = b2f(base[(size_t)(h0 + 0) * 65536 + o]);
    v.y = b2f(base[(size_t)(h0 + 1) * 65536 + o]);
    v.z = b2f(base[(size_t)(h0 + 2) * 65536 + o]);
    v.w = b2f(base[(size_t)(h0 + 3) * 65536 + o]);
  } else {
    short4 s4 = ((const short4*)((const short*)xin + (size_t)row * 1024))[tid];
    v.x = b2f(s4.x); v.y = b2f(s4.y); v.z = b2f(s4.z); v.w = b2f(s4.w);
  }
  float s = v.x + v.y + v.z + v.w;
  float sq = v.x * v.x + v.y * v.y + v.z * v.z + v.w * v.w;
  #pragma unroll
  for (int off = 32; off > 0; off >>= 1) {
    s += __shfl_down(s, off, 64);
    sq += __shfl_down(sq, off, 64);
  }
  __shared__ float rs[4], rq[4], stat[2];
  int wave = tid >> 6, lane = tid & 63;
  if (lane == 0) { rs[wave] = s; rq[wave] = sq; }
  __syncthreads();
  if (tid == 0) {
    float S = rs[0] + rs[1] + rs[2] + rs[3];
    float Q = rq[0] + rq[1] + rq[2] + rq[3];
    float mean = S * (1.f / 1024.f);
    float var = Q * (1.f / 1024.f) - mean * mean;
    stat[0] = mean;
    stat[1] = rsqrtf(var + 1e-5f);
  }
  __syncthreads();
  float mean = stat[0], rstd = stat[1];
  float4 g4 = ((const float4*)g)[tid];
  float4 b4 = ((const float4*)be)[tid];
  short4 r4 = ((const short4*)(res + (size_t)row * 1024))[tid];
  float o0 = (v.x - mean) * rstd * g4.x + b4.x + b2f(r4.x);
  float o1 = (v.y - mean) * rstd * g4.y + b4.y + b2f(r4.y);
  float o2 = (v.z - mean) * rstd * g4.z + b4.z + b2f(r4.z);
  float o3 = (v.w - mean) * rstd * g4.w + b4.w + b2f(r4.w);
  if (out_bf16) {
    short4 o;
    o.x = f2b(o0); o.y = f2b(o1); o.z = f2b(o2); o.w = f2b(o3);
    ((short4*)outp)[(size_t)row * 256 + tid] = o;
  } else {
    float4 o = {o0, o1, o2, o3};
    ((float4*)outp)[(size_t)row * 256 + tid] = o;
  }
}

// ---------------------------------------------------------------------------
extern "C" void kernel_launch(void* const* d_in, const int* in_sizes, int n_in,
                              void* d_out, int out_size, void* d_ws, size_t ws_size,
                              hipStream_t stream) {
  const float* x    = (const float*)d_in[0];
  const float* ctx  = (const float*)d_in[1];
  const float* cm   = (const float*)d_in[2];
  const float* ppm  = (const float*)d_in[3];
  const float* cpm  = (const float*)d_in[4];
  const float* saWq = (const float*)d_in[5];
  const float* sabq = (const float*)d_in[6];
  const float* saWk = (const float*)d_in[7];
  const float* sabk = (const float*)d_in[8];
  const float* saWv = (const float*)d_in[9];
  const float* sabv = (const float*)d_in[10];
  const float* caWq = (const float*)d_in[11];
  const float* cabq = (const float*)d_in[12];
  const float* caWk = (const float*)d_in[13];
  const float* cabk = (const float*)d_in[14];
  const float* caWv = (const float*)d_in[15];
  const float* cabv = (const float*)d_in[16];
  const float* ln1g = (const float*)d_in[17];
  const float* ln1b = (const float*)d_in[18];
  const float* ln2g = (const float*)d_in[19];
  const float* ln2b = (const float*)d_in[20];
  const float* ln3g = (const float*)d_in[21];
  const float* ln3b = (const float*)d_in[22];
  const float* W1   = (const float*)d_in[23];
  const float* b1   = (const float*)d_in[24];
  const float* W2   = (const float*)d_in[25];
  const float* b2   = (const float*)d_in[26];

  char* ws = (char*)d_ws;
  const size_t MB = 1024 * 1024;
  short* WT       = (short*)(ws);              // 8 x 2MB bf16 [n'][k]
  float* qkvb     = (float*)(ws + 16 * MB);
  float* kvb      = (float*)(ws + 16 * MB + 16384);
  float* qpb      = (float*)(ws + 16 * MB + 32768);
  unsigned* kmaxu = (unsigned*)(ws + 16 * MB + 49152);  // 64 kmax + 2 flags
  unsigned* mflags = kmaxu + 64;
  short* MBSA  = (short*)(ws + 17 * MB);
  short* MBCA  = (short*)(ws + 21 * MB);
  short* XB    = (short*)(ws + 25 * MB);
  short* CTXB  = (short*)(ws + 29 * MB);
  short* QH    = (short*)(ws + 33 * MB);
  short* KH    = (short*)(ws + 37 * MB);
  short* VT    = (short*)(ws + 41 * MB);
  short* S3B   = (short*)(ws + 45 * MB);
  short* X1B   = (short*)(ws + 53 * MB);
  short* X2B   = MBSA;
  short* HB    = CTXB;
  float* outp  = (float*)d_out;

  dim3 lg(2048);
  const short* dsp = nullptr;
  const float* dfp = nullptr;

  // 0: zero control words
  initk<<<dim3(1), 128, 0, stream>>>(kmaxu);

  // 1: prep + weight transpose (+ mask nonzero flags)
  prep_wt<<<dim3(10264), 256, 0, stream>>>(
      x, ctx, cm, ppm, cpm, sabq, sabk, sabv, cabk, cabv, cabq,
      saWq, saWk, saWv, caWk, caWv, caWq, W1, W2,
      XB, CTXB, MBSA, MBCA, qkvb, kvb, qpb, mflags, WT);

  // 2: QKV (self), kmax fused
  gemmT<128><<<dim3(32, 24, 1), 256, 0, stream>>>(
      XB, WT, qkvb, QH, KH, VT, 3, 0, 24,
      dsp, dsp, dfp, nullptr, nullptr, nullptr, 0, 0, 0, kmaxu);

  // 3-4: self attention + LN1
  attn_flash<<<dim3(16, 16, 2), 256, 0, stream>>>(QH, KH, VT, MBSA, kmaxu,
                                                  S3B, mflags);
  ln_kernel<<<lg, 256, 0, stream>>>(S3B, XB, ln1g, ln1b, X1B, 1, 1);

  // 5: cross Q (z=0) + cross KV (z=1), kmax fused
  gemmT<128><<<dim3(32, 16, 2), 256, 0, stream>>>(
      X1B, WT + 5 * 1048576, qpb, QH, nullptr, nullptr, 2, 0, 8,
      CTXB, WT + 3 * 1048576, kvb, nullptr, KH, VT, 4, 0, 16, kmaxu);

  // 6-7: cross attention + LN2
  attn_flash<<<dim3(16, 16, 2), 256, 0, stream>>>(QH, KH, VT, MBCA,
                                                  kmaxu + 32, S3B, mflags + 1);
  ln_kernel<<<lg, 256, 0, stream>>>(S3B, X1B, ln2g, ln2b, X2B, 1, 1);

  // 8-10: MLP + LN3
  gemmT<64><<<dim3(32, 16, 1), 256, 0, stream>>>(
      X2B, WT + 6 * 1048576, b1, HB, nullptr, nullptr, 1, 1, 16,
      dsp, dsp, dfp, nullptr, nullptr, nullptr, 0, 0, 0, kmaxu);
  gemmT<64><<<dim3(32, 16, 1), 256, 0, stream>>>(
      HB, WT + 7 * 1048576, b2, S3B, nullptr, nullptr, 1, 0, 16,
      dsp, dsp, dfp, nullptr, nullptr, nullptr, 0, 0, 0, kmaxu);
  ln_kernel<<<lg, 256, 0, stream>>>(S3B, X2B, ln3g, ln3b, outp, 0, 2);
}